// Round 1
// baseline (294.003 us; speedup 1.0000x reference)
//
#include <hip/hip_runtime.h>

typedef unsigned short u16;
typedef short bf16x8 __attribute__((ext_vector_type(8)));
typedef u16 u16x8 __attribute__((ext_vector_type(8)));
typedef float f32x4 __attribute__((ext_vector_type(4)));

// ---------------- helpers ----------------

__device__ __forceinline__ u16 f2bf(float f) {
  unsigned u = __float_as_uint(f);
  u += 0x7FFFu + ((u >> 16) & 1u);   // RNE
  return (u16)(u >> 16);
}

typedef const void __attribute__((address_space(1)))* gas_p;
typedef void __attribute__((address_space(3)))* las_p;

__device__ __forceinline__ void async_ld16(const void* g, void* l) {
  __builtin_amdgcn_global_load_lds((gas_p)g, (las_p)l, 16, 0, 0);
}

// ---------------- convert x -> bf16 ----------------

__global__ __launch_bounds__(256) void k_cvt_bf16(const float* __restrict__ in,
                                                  u16* __restrict__ out, int n8) {
  int i = blockIdx.x * 256 + threadIdx.x;
  if (i >= n8) return;
  const float4* p = (const float4*)in + (size_t)i * 2;
  float4 a = p[0], b = p[1];
  u16x8 o;
  o[0] = f2bf(a.x); o[1] = f2bf(a.y); o[2] = f2bf(a.z); o[3] = f2bf(a.w);
  o[4] = f2bf(b.x); o[5] = f2bf(b.y); o[6] = f2bf(b.z); o[7] = f2bf(b.w);
  *((u16x8*)out + i) = o;
}

// ---------------- transpose + convert W[K][N] -> Wt[N][K] bf16 ----------------

__global__ __launch_bounds__(256) void k_transpose_cvt(const float* __restrict__ in,
                                                       u16* __restrict__ out,
                                                       int R, int Ncols) {
  __shared__ u16 t[32][33];
  int tx = threadIdx.x, ty = threadIdx.y;
  int c0 = blockIdx.x * 32, r0 = blockIdx.y * 32;
#pragma unroll
  for (int j = 0; j < 32; j += 8)
    t[ty + j][tx] = f2bf(in[(size_t)(r0 + ty + j) * Ncols + c0 + tx]);
  __syncthreads();
#pragma unroll
  for (int j = 0; j < 32; j += 8)
    out[(size_t)(c0 + ty + j) * R + r0 + tx] = t[tx][ty + j];
}

// ---------------- bf16 GEMM: C[M][N] = A[M][K] * Bt[N][K]^T + bias ----------------
// m97-style: 128x128 tile, BK=32, 4 waves (2x2), global_load_lds width 16.

template <int OUT_BF16>
__global__ __launch_bounds__(256) void k_gemm_bf16(const u16* __restrict__ A,
                                                   const u16* __restrict__ Bt,
                                                   const float* __restrict__ bias,
                                                   void* __restrict__ Cout,
                                                   int M, int N, int K) {
  __shared__ u16 As[128 * 32];
  __shared__ u16 Bs[128 * 32];

  int nbn = N >> 7;
  int nbm = M >> 7;
  int nwg = nbm * nbn;
  int bid = blockIdx.x;
  // bijective XCD swizzle (m204)
  int q = nwg >> 3, r = nwg & 7, x = bid & 7, loc = bid >> 3;
  int swz = (x < r ? x * (q + 1) : r * (q + 1) + (x - r) * q) + loc;
  int mi = swz / nbn, ni = swz % nbn;
  int m0 = mi << 7, n0 = ni << 7;

  int tid = threadIdx.x;
  int w = tid >> 6, lane = tid & 63;
  int wr = w >> 1, wc = w & 1;

  // staging: per wave, 2 insts for A (16 rows each) + 2 for B
  const u16* a0 = A + (size_t)(m0 + w * 32 + (lane >> 2)) * K + ((lane & 3) << 3);
  const u16* a1 = a0 + (size_t)16 * K;
  const u16* b0 = Bt + (size_t)(n0 + w * 32 + (lane >> 2)) * K + ((lane & 3) << 3);
  const u16* b1 = b0 + (size_t)16 * K;
  u16* sA0 = As + (w * 32) * 32;       // wave-uniform LDS bases
  u16* sA1 = As + (w * 32 + 16) * 32;
  u16* sB0 = Bs + (w * 32) * 32;
  u16* sB1 = Bs + (w * 32 + 16) * 32;

  const u16* fA = As + ((wr * 64 + (lane & 15)) * 32 + ((lane >> 4) << 3));
  const u16* fB = Bs + ((wc * 64 + (lane & 15)) * 32 + ((lane >> 4) << 3));

  f32x4 acc[4][4] = {};

  for (int k0 = 0; k0 < K; k0 += 32) {
    async_ld16(a0, sA0);
    async_ld16(a1, sA1);
    async_ld16(b0, sB0);
    async_ld16(b1, sB1);
    a0 += 32; a1 += 32; b0 += 32; b1 += 32;
    __syncthreads();   // compiler drains vmcnt before barrier
    bf16x8 af[4], bfr[4];
#pragma unroll
    for (int i = 0; i < 4; ++i) {
      af[i] = *(const bf16x8*)(fA + i * 16 * 32);
      bfr[i] = *(const bf16x8*)(fB + i * 16 * 32);
    }
#pragma unroll
    for (int m = 0; m < 4; ++m)
#pragma unroll
      for (int n = 0; n < 4; ++n)
        acc[m][n] = __builtin_amdgcn_mfma_f32_16x16x32_bf16(af[m], bfr[n], acc[m][n], 0, 0, 0);
    __syncthreads();
  }

  // epilogue: D row = 4*(lane>>4)+reg, col = lane&15
#pragma unroll
  for (int m = 0; m < 4; ++m)
#pragma unroll
    for (int n = 0; n < 4; ++n) {
      int gr = m0 + wr * 64 + m * 16 + ((lane >> 4) << 2);
      int gc = n0 + wc * 64 + n * 16 + (lane & 15);
      float bv = bias[gc];
#pragma unroll
      for (int reg = 0; reg < 4; ++reg) {
        float v = acc[m][n][reg] + bv;
        if (OUT_BF16)
          ((u16*)Cout)[(size_t)(gr + reg) * N + gc] = f2bf(v);
        else
          ((float*)Cout)[(size_t)(gr + reg) * N + gc] = v;
      }
    }
}

// ---------------- block-diagonal attention ----------------
// grid: B*H*NB*4 = 4096 blocks, 256 threads (4 waves), each wave = 16 q rows.
// qkv: bf16 [16384][3072], col = h*192 + {0,64,128} + d. o: bf16 [16384][1024].

__global__ __launch_bounds__(256) void k_attn(const u16* __restrict__ qkv,
                                              u16* __restrict__ o) {
  __shared__ u16 ldsK[256 * 64];   // swizzled K; reused as P after S phase
  __shared__ u16 ldsV[64 * 256];   // V transposed [d][t], swizzled

  int nwg = gridDim.x;
  int bid = blockIdx.x;
  int q_ = nwg >> 3, r_ = nwg & 7, x_ = bid & 7, loc = bid >> 3;
  int g = (x_ < r_ ? x_ * (q_ + 1) : r_ * (q_ + 1) + (x_ - r_) * q_) + loc;

  int quarter = g & 3;
  int blk = (g >> 2) & 15;
  int h = (g >> 6) & 15;
  int b = g >> 10;

  int tid = threadIdx.x;
  int w = tid >> 6, lane = tid & 63;

  size_t rowb = ((size_t)(b * 4096 + blk * 256)) * 3072 + (size_t)h * 192;

  // ---- stage K (swizzled) and V (transposed, swizzled) ----
  for (int it = 0; it < 8; ++it) {
    int t = it * 32 + (tid >> 3);
    int d0 = (tid & 7) << 3;
    const u16* src = qkv + rowb + (size_t)t * 3072;
    uint4 kv = *(const uint4*)(src + 64 + d0);
    *(uint4*)((char*)ldsK + t * 128 + ((2 * d0) ^ ((t & 7) << 4))) = kv;
    uint4 vv = *(const uint4*)(src + 128 + d0);
    union { uint4 v; u16 s[8]; } uv;
    uv.v = vv;
#pragma unroll
    for (int j = 0; j < 8; ++j) {
      int d = d0 + j;
      int key = (((d & 7) ^ ((d >> 3) & 7)) & 7) << 4;
      *(u16*)((char*)ldsV + d * 512 + ((2 * t) ^ key)) = uv.s[j];
    }
  }

  // ---- Q fragments in registers (A-operand: row = lane&15, 8 contiguous k) ----
  int qrow = quarter * 64 + w * 16 + (lane & 15);
  const u16* qp = qkv + rowb + (size_t)qrow * 3072;
  bf16x8 qf0 = *(const bf16x8*)(qp + ((lane >> 4) << 3));
  bf16x8 qf1 = *(const bf16x8*)(qp + 32 + ((lane >> 4) << 3));

  __syncthreads();

  // ---- S = Q K^T : acc[ct] covers cols ct*16..ct*16+15 for 16 q rows ----
  f32x4 acc[16] = {};
#pragma unroll
  for (int ct = 0; ct < 16; ++ct) {
    int krow = ct * 16 + (lane & 15);
    const char* kb = (const char*)ldsK + krow * 128;
    int key = (krow & 7) << 4;
    int cb = (lane >> 4) << 4;  // byte offset of 8 bf16 = 16*(lane>>4)
    bf16x8 k0 = *(const bf16x8*)(kb + ((cb) ^ key));
    bf16x8 k1 = *(const bf16x8*)(kb + ((64 + cb) ^ key));
    acc[ct] = __builtin_amdgcn_mfma_f32_16x16x32_bf16(qf0, k0, acc[ct], 0, 0, 0);
    acc[ct] = __builtin_amdgcn_mfma_f32_16x16x32_bf16(qf1, k1, acc[ct], 0, 0, 0);
  }

  // ---- softmax over 256 cols; rows live at (lane>>4)*4+reg, cols at ct*16+(lane&15) ----
  const float SC = 0.125f * 1.44269504f;  // scale * log2(e)
  float rden[4];
#pragma unroll
  for (int reg = 0; reg < 4; ++reg) {
    float mx = -1e30f;
#pragma unroll
    for (int ct = 0; ct < 16; ++ct) mx = fmaxf(mx, acc[ct][reg]);
    mx = fmaxf(mx, __shfl_xor(mx, 1));
    mx = fmaxf(mx, __shfl_xor(mx, 2));
    mx = fmaxf(mx, __shfl_xor(mx, 4));
    mx = fmaxf(mx, __shfl_xor(mx, 8));
    float s = 0.f;
#pragma unroll
    for (int ct = 0; ct < 16; ++ct) {
      float p = exp2f((acc[ct][reg] - mx) * SC);
      acc[ct][reg] = p;
      s += p;
    }
    s += __shfl_xor(s, 1);
    s += __shfl_xor(s, 2);
    s += __shfl_xor(s, 4);
    s += __shfl_xor(s, 8);
    rden[reg] = 1.f / s;
  }

  __syncthreads();  // all waves done reading K -> safe to overwrite with P

  // ---- write P (unnormalized, bf16) into per-wave region of ldsK ----
  char* Pb = (char*)(ldsK + w * 4096);  // 16x256 bf16 = 8KB per wave
#pragma unroll
  for (int ct = 0; ct < 16; ++ct)
#pragma unroll
    for (int reg = 0; reg < 4; ++reg) {
      int prow = ((lane >> 4) << 2) + reg;
      int pcol = ct * 16 + (lane & 15);
      *(u16*)(Pb + prow * 512 + ((2 * pcol) ^ ((prow & 7) << 4))) = f2bf(acc[ct][reg]);
    }

  __syncthreads();

  // ---- O = P V ----
  f32x4 oacc[4] = {};
#pragma unroll
  for (int kt = 0; kt < 8; ++kt) {
    int prow = lane & 15;
    bf16x8 pf = *(const bf16x8*)(Pb + prow * 512 +
                                 ((2 * (kt * 32 + ((lane >> 4) << 3))) ^ ((prow & 7) << 4)));
#pragma unroll
    for (int nt = 0; nt < 4; ++nt) {
      int vd = nt * 16 + (lane & 15);
      int vk = kt * 32 + ((lane >> 4) << 3);
      int key = (((vd & 7) ^ ((vd >> 3) & 7)) & 7) << 4;
      bf16x8 vf = *(const bf16x8*)((char*)ldsV + vd * 512 + ((2 * vk) ^ key));
      oacc[nt] = __builtin_amdgcn_mfma_f32_16x16x32_bf16(pf, vf, oacc[nt], 0, 0, 0);
    }
  }

  // ---- epilogue: normalize rows (same lane mapping as S rows), write o ----
  size_t obase = ((size_t)(b * 4096 + blk * 256 + quarter * 64 + w * 16)) * 1024 + h * 64;
#pragma unroll
  for (int nt = 0; nt < 4; ++nt)
#pragma unroll
    for (int reg = 0; reg < 4; ++reg) {
      int orow = ((lane >> 4) << 2) + reg;
      int od = nt * 16 + (lane & 15);
      o[obase + (size_t)orow * 1024 + od] = f2bf(oacc[nt][reg] * rden[reg]);
    }
}

// ---------------- launch ----------------

extern "C" void kernel_launch(void* const* d_in, const int* in_sizes, int n_in,
                              void* d_out, int out_size, void* d_ws, size_t ws_size,
                              hipStream_t stream) {
  (void)in_sizes; (void)n_in; (void)out_size; (void)ws_size;
  const float* x = (const float*)d_in[0];     // [16384][1024]
  const float* Wqkv = (const float*)d_in[1];  // [1024][3072]
  const float* bqkv = (const float*)d_in[2];  // [3072]
  const float* Wout = (const float*)d_in[3];  // [1024][1024]
  const float* bout = (const float*)d_in[4];  // [1024]
  float* out = (float*)d_out;                 // [16384][1024]

  char* ws = (char*)d_ws;
  u16* xb    = (u16*)(ws + 0);          // 33,554,432 B
  u16* wqkvT = (u16*)(ws + 33554432);   //  6,291,456 B
  u16* woT   = (u16*)(ws + 39845888);   //  2,097,152 B
  u16* qkv   = (u16*)(ws + 41943040);   // 100,663,296 B
  u16* ob    = (u16*)(ws + 142606336);  // 33,554,432 B  (total 176,160,768)

  // converts
  k_cvt_bf16<<<8192, 256, 0, stream>>>(x, xb, 16384 * 1024 / 8);
  k_transpose_cvt<<<dim3(96, 32), dim3(32, 8), 0, stream>>>(Wqkv, wqkvT, 1024, 3072);
  k_transpose_cvt<<<dim3(32, 32), dim3(32, 8), 0, stream>>>(Wout, woT, 1024, 1024);

  // qkv = x @ Wqkv + bqkv  (bf16 out)
  k_gemm_bf16<1><<<128 * 24, 256, 0, stream>>>(xb, wqkvT, bqkv, qkv, 16384, 3072, 1024);

  // block-diagonal attention
  k_attn<<<4096, 256, 0, stream>>>(qkv, ob);

  // out = o @ Wout + bout  (fp32 out)
  k_gemm_bf16<0><<<128 * 8, 256, 0, stream>>>(ob, woT, bout, out, 16384, 1024, 1024);
}

// Round 2
// 240.730 us; speedup vs baseline: 1.2213x; 1.2213x over previous
//
#include <hip/hip_runtime.h>

typedef unsigned short u16;
typedef short bf16x8 __attribute__((ext_vector_type(8)));
typedef u16 u16x8 __attribute__((ext_vector_type(8)));
typedef float f32x4 __attribute__((ext_vector_type(4)));

// ---------------- helpers ----------------

__device__ __forceinline__ u16 f2bf(float f) {
  unsigned u = __float_as_uint(f);
  u += 0x7FFFu + ((u >> 16) & 1u);   // RNE
  return (u16)(u >> 16);
}

typedef const void __attribute__((address_space(1)))* gas_p;
typedef void __attribute__((address_space(3)))* las_p;

__device__ __forceinline__ void async_ld16(const void* g, void* l) {
  __builtin_amdgcn_global_load_lds((gas_p)g, (las_p)l, 16, 0, 0);
}

// ---------------- convert x -> bf16 ----------------

__global__ __launch_bounds__(256) void k_cvt_bf16(const float* __restrict__ in,
                                                  u16* __restrict__ out, int n8) {
  int i = blockIdx.x * 256 + threadIdx.x;
  if (i >= n8) return;
  const float4* p = (const float4*)in + (size_t)i * 2;
  float4 a = p[0], b = p[1];
  u16x8 o;
  o[0] = f2bf(a.x); o[1] = f2bf(a.y); o[2] = f2bf(a.z); o[3] = f2bf(a.w);
  o[4] = f2bf(b.x); o[5] = f2bf(b.y); o[6] = f2bf(b.z); o[7] = f2bf(b.w);
  *((u16x8*)out + i) = o;
}

// ---------------- transpose + convert W[K][N] -> Wt[N][K] bf16 ----------------

__global__ __launch_bounds__(256) void k_transpose_cvt(const float* __restrict__ in,
                                                       u16* __restrict__ out,
                                                       int R, int Ncols) {
  __shared__ u16 t[32][33];
  int tx = threadIdx.x, ty = threadIdx.y;
  int c0 = blockIdx.x * 32, r0 = blockIdx.y * 32;
#pragma unroll
  for (int j = 0; j < 32; j += 8)
    t[ty + j][tx] = f2bf(in[(size_t)(r0 + ty + j) * Ncols + c0 + tx]);
  __syncthreads();
#pragma unroll
  for (int j = 0; j < 32; j += 8)
    out[(size_t)(c0 + ty + j) * R + r0 + tx] = t[tx][ty + j];
}

// ---------------- 256^2 8-phase bf16 GEMM ----------------
// C[M][N] = A[M][K] * Bt[N][K]^T + bias.  BM=BN=256, BK=64, 8 waves (2x4),
// 512 threads, 128KB LDS double-buffered, T2 granule-XOR swizzle,
// T3/T4 counted vmcnt, T5 setprio.

#define MFMA2(m, n)                                                                   \
  acc[m][n] = __builtin_amdgcn_mfma_f32_16x16x32_bf16(a[m][0], b[n][0], acc[m][n], 0, 0, 0); \
  acc[m][n] = __builtin_amdgcn_mfma_f32_16x16x32_bf16(a[m][1], b[n][1], acc[m][n], 0, 0, 0);

#define STAGE_A(h_, T_, dd_) do {                                          \
    const u16* g_ = pAg + (size_t)(h_) * 128 * KK + (size_t)(T_) * 64;     \
    u16* s_ = lds + (dd_) * 16384 + ((h_) * 128 + w * 16) * 64;            \
    async_ld16(g_, s_);                                                    \
    async_ld16(g_ + 8 * (size_t)KK, s_ + 512);                             \
  } while (0)

#define STAGE_B(h_, T_, dd_) do {                                          \
    const u16* g_ = pBg + (size_t)(h_) * 128 * KK + (size_t)(T_) * 64;     \
    u16* s_ = lds + 32768 + (dd_) * 16384 + ((h_) * 128 + w * 16) * 64;    \
    async_ld16(g_, s_);                                                    \
    async_ld16(g_ + 8 * (size_t)KK, s_ + 512);                             \
  } while (0)

#define TB(k_, d_)                                                              \
  {                                                                             \
    const int doA = (d_) * 16384, doB = 32768 + (d_) * 16384;                   \
    /* ---- phase 1: read A frags 0-3 + B frags 0-1; stage Bh0(k+1) ---- */     \
    _Pragma("unroll") for (int f = 0; f < 4; ++f) {                             \
      a[f][0] = *(const bf16x8*)(lds + doA + rAoff + f * 1024 + c0);            \
      a[f][1] = *(const bf16x8*)(lds + doA + rAoff + f * 1024 + c1);            \
    }                                                                           \
    _Pragma("unroll") for (int f = 0; f < 2; ++f) {                             \
      b[f][0] = *(const bf16x8*)(lds + doB + rBoff + f * 1024 + c0);            \
      b[f][1] = *(const bf16x8*)(lds + doB + rBoff + f * 1024 + c1);            \
    }                                                                           \
    if ((k_) + 1 < NT) STAGE_B(0, (k_) + 1, (d_) ^ 1);                          \
    asm volatile("s_waitcnt lgkmcnt(8)");                                       \
    __builtin_amdgcn_s_barrier();                                               \
    asm volatile("s_waitcnt lgkmcnt(0)");                                       \
    __builtin_amdgcn_s_setprio(1);                                              \
    MFMA2(0, 0); MFMA2(1, 0); MFMA2(2, 0); MFMA2(3, 0);                         \
    MFMA2(0, 1); MFMA2(1, 1); MFMA2(2, 1); MFMA2(3, 1);                         \
    __builtin_amdgcn_s_setprio(0);                                              \
    __builtin_amdgcn_s_barrier();                                               \
    /* ---- phase 2: read A frags 4-7; stage Bh1(k+1) ---- */                   \
    _Pragma("unroll") for (int f = 4; f < 8; ++f) {                             \
      a[f][0] = *(const bf16x8*)(lds + doA + rAoff + f * 1024 + c0);            \
      a[f][1] = *(const bf16x8*)(lds + doA + rAoff + f * 1024 + c1);            \
    }                                                                           \
    if ((k_) + 1 < NT) STAGE_B(1, (k_) + 1, (d_) ^ 1);                          \
    __builtin_amdgcn_s_barrier();                                               \
    asm volatile("s_waitcnt lgkmcnt(0)");                                       \
    __builtin_amdgcn_s_setprio(1);                                              \
    MFMA2(4, 0); MFMA2(5, 0); MFMA2(6, 0); MFMA2(7, 0);                         \
    MFMA2(4, 1); MFMA2(5, 1); MFMA2(6, 1); MFMA2(7, 1);                         \
    __builtin_amdgcn_s_setprio(0);                                              \
    __builtin_amdgcn_s_barrier();                                               \
    /* ---- phase 3: read B frags 2-3; stage Ah0(k+2) ---- */                   \
    _Pragma("unroll") for (int f = 2; f < 4; ++f) {                             \
      b[f][0] = *(const bf16x8*)(lds + doB + rBoff + f * 1024 + c0);            \
      b[f][1] = *(const bf16x8*)(lds + doB + rBoff + f * 1024 + c1);            \
    }                                                                           \
    if ((k_) + 2 < NT) STAGE_A(0, (k_) + 2, (d_));                              \
    __builtin_amdgcn_s_barrier();                                               \
    asm volatile("s_waitcnt lgkmcnt(0)");                                       \
    __builtin_amdgcn_s_setprio(1);                                              \
    MFMA2(4, 2); MFMA2(5, 2); MFMA2(6, 2); MFMA2(7, 2);                         \
    MFMA2(4, 3); MFMA2(5, 3); MFMA2(6, 3); MFMA2(7, 3);                         \
    __builtin_amdgcn_s_setprio(0);                                              \
    __builtin_amdgcn_s_barrier();                                               \
    /* ---- phase 4: no reads; stage Ah1(k+2); counted vmcnt ---- */            \
    if ((k_) + 2 < NT) STAGE_A(1, (k_) + 2, (d_));                              \
    __builtin_amdgcn_s_setprio(1);                                              \
    MFMA2(0, 2); MFMA2(1, 2); MFMA2(2, 2); MFMA2(3, 2);                         \
    MFMA2(0, 3); MFMA2(1, 3); MFMA2(2, 3); MFMA2(3, 3);                         \
    __builtin_amdgcn_s_setprio(0);                                              \
    if ((k_) < NT - 2) { asm volatile("s_waitcnt vmcnt(4)"); }                  \
    else               { asm volatile("s_waitcnt vmcnt(0)"); }                  \
    __builtin_amdgcn_s_barrier();                                               \
  }

template <int OUT_BF16, int KK>
__global__ __launch_bounds__(512, 2) void k_gemm8(const u16* __restrict__ A,
                                                  const u16* __restrict__ Bt,
                                                  const float* __restrict__ bias,
                                                  void* __restrict__ Cout,
                                                  int M, int N) {
  extern __shared__ u16 lds[];   // [A dbuf0][A dbuf1][B dbuf0][B dbuf1], 4x32KB
  const int NT = KK / 64;

  int nbn = N >> 8, nbm = M >> 8, nwg = nbm * nbn;
  int bid = blockIdx.x;
  int q = nwg >> 3, r = nwg & 7, x = bid & 7, loc = bid >> 3;
  int swz = (x < r ? x * (q + 1) : r * (q + 1) + (x - r) * q) + loc;
  int mi = swz / nbn, ni = swz % nbn;
  int m0 = mi << 8, n0 = ni << 8;

  int tid = threadIdx.x;
  int w = tid >> 6, lane = tid & 63;
  int wm = w >> 2, wn = w & 3;      // wave grid 2 (M) x 4 (N)

  // ds_read addressing: row stride 64 elems; 16B granule at position
  // (ks*4 + lane>>4) ^ (row&7); row&7 == lane&7 for all fragments.
  int rAoff = (wm * 128 + (lane & 15)) << 6;
  int rBoff = (wn * 64 + (lane & 15)) << 6;
  int hi8 = (lane >> 4) << 3, key8 = (lane & 7) << 3;
  int c0 = hi8 ^ key8;
  int c1 = (32 | hi8) ^ key8;

  // staging: linear LDS dest, inverse-swizzled global source
  const u16* pAg = A + (size_t)(m0 + w * 16 + (lane >> 3)) * KK +
                   (((lane & 7) ^ (lane >> 3)) << 3);
  const u16* pBg = Bt + (size_t)(n0 + w * 16 + (lane >> 3)) * KK +
                   (((lane & 7) ^ (lane >> 3)) << 3);

  bf16x8 a[8][2], b[4][2];
  f32x4 acc[8][4] = {};

  // prologue: tile0 fully + tile1 A-halves; leave tile1-A in flight
  STAGE_A(0, 0, 0); STAGE_A(1, 0, 0); STAGE_B(0, 0, 0); STAGE_B(1, 0, 0);
  STAGE_A(0, 1, 1); STAGE_A(1, 1, 1);
  asm volatile("s_waitcnt vmcnt(4)");
  __builtin_amdgcn_s_barrier();

  for (int k = 0; k < NT; k += 2) {
    TB(k, 0);
    TB(k + 1, 1);
  }

  // epilogue: D row = 4*(lane>>4)+reg, col = lane&15
  int ccol0 = n0 + wn * 64 + (lane & 15);
  float bv[4] = {bias[ccol0], bias[ccol0 + 16], bias[ccol0 + 32], bias[ccol0 + 48]};
  size_t crow0 = (size_t)(m0 + wm * 128 + ((lane >> 4) << 2));
#pragma unroll
  for (int m = 0; m < 8; ++m)
#pragma unroll
    for (int reg = 0; reg < 4; ++reg) {
      size_t ro = (crow0 + m * 16 + reg) * (size_t)N + ccol0;
#pragma unroll
      for (int n = 0; n < 4; ++n) {
        float v = acc[m][n][reg] + bv[n];
        if (OUT_BF16) ((u16*)Cout)[ro + n * 16] = f2bf(v);
        else          ((float*)Cout)[ro + n * 16] = v;
      }
    }
}

// ---------------- block-diagonal attention (unchanged, validated) ----------------

__global__ __launch_bounds__(256) void k_attn(const u16* __restrict__ qkv,
                                              u16* __restrict__ o) {
  __shared__ u16 ldsK[256 * 64];   // swizzled K; reused as P after S phase
  __shared__ u16 ldsV[64 * 256];   // V transposed [d][t], swizzled

  int nwg = gridDim.x;
  int bid = blockIdx.x;
  int q_ = nwg >> 3, r_ = nwg & 7, x_ = bid & 7, loc = bid >> 3;
  int g = (x_ < r_ ? x_ * (q_ + 1) : r_ * (q_ + 1) + (x_ - r_) * q_) + loc;

  int quarter = g & 3;
  int blk = (g >> 2) & 15;
  int h = (g >> 6) & 15;
  int b = g >> 10;

  int tid = threadIdx.x;
  int w = tid >> 6, lane = tid & 63;

  size_t rowb = ((size_t)(b * 4096 + blk * 256)) * 3072 + (size_t)h * 192;

  for (int it = 0; it < 8; ++it) {
    int t = it * 32 + (tid >> 3);
    int d0 = (tid & 7) << 3;
    const u16* src = qkv + rowb + (size_t)t * 3072;
    uint4 kv = *(const uint4*)(src + 64 + d0);
    *(uint4*)((char*)ldsK + t * 128 + ((2 * d0) ^ ((t & 7) << 4))) = kv;
    uint4 vv = *(const uint4*)(src + 128 + d0);
    union { uint4 v; u16 s[8]; } uv;
    uv.v = vv;
#pragma unroll
    for (int j = 0; j < 8; ++j) {
      int d = d0 + j;
      int key = (((d & 7) ^ ((d >> 3) & 7)) & 7) << 4;
      *(u16*)((char*)ldsV + d * 512 + ((2 * t) ^ key)) = uv.s[j];
    }
  }

  int qrow = quarter * 64 + w * 16 + (lane & 15);
  const u16* qp = qkv + rowb + (size_t)qrow * 3072;
  bf16x8 qf0 = *(const bf16x8*)(qp + ((lane >> 4) << 3));
  bf16x8 qf1 = *(const bf16x8*)(qp + 32 + ((lane >> 4) << 3));

  __syncthreads();

  f32x4 acc[16] = {};
#pragma unroll
  for (int ct = 0; ct < 16; ++ct) {
    int krow = ct * 16 + (lane & 15);
    const char* kb = (const char*)ldsK + krow * 128;
    int key = (krow & 7) << 4;
    int cb = (lane >> 4) << 4;
    bf16x8 k0 = *(const bf16x8*)(kb + ((cb) ^ key));
    bf16x8 k1 = *(const bf16x8*)(kb + ((64 + cb) ^ key));
    acc[ct] = __builtin_amdgcn_mfma_f32_16x16x32_bf16(qf0, k0, acc[ct], 0, 0, 0);
    acc[ct] = __builtin_amdgcn_mfma_f32_16x16x32_bf16(qf1, k1, acc[ct], 0, 0, 0);
  }

  const float SC = 0.125f * 1.44269504f;
  float rden[4];
#pragma unroll
  for (int reg = 0; reg < 4; ++reg) {
    float mx = -1e30f;
#pragma unroll
    for (int ct = 0; ct < 16; ++ct) mx = fmaxf(mx, acc[ct][reg]);
    mx = fmaxf(mx, __shfl_xor(mx, 1));
    mx = fmaxf(mx, __shfl_xor(mx, 2));
    mx = fmaxf(mx, __shfl_xor(mx, 4));
    mx = fmaxf(mx, __shfl_xor(mx, 8));
    float s = 0.f;
#pragma unroll
    for (int ct = 0; ct < 16; ++ct) {
      float p = exp2f((acc[ct][reg] - mx) * SC);
      acc[ct][reg] = p;
      s += p;
    }
    s += __shfl_xor(s, 1);
    s += __shfl_xor(s, 2);
    s += __shfl_xor(s, 4);
    s += __shfl_xor(s, 8);
    rden[reg] = 1.f / s;
  }

  __syncthreads();

  char* Pb = (char*)(ldsK + w * 4096);
#pragma unroll
  for (int ct = 0; ct < 16; ++ct)
#pragma unroll
    for (int reg = 0; reg < 4; ++reg) {
      int prow = ((lane >> 4) << 2) + reg;
      int pcol = ct * 16 + (lane & 15);
      *(u16*)(Pb + prow * 512 + ((2 * pcol) ^ ((prow & 7) << 4))) = f2bf(acc[ct][reg]);
    }

  __syncthreads();

  f32x4 oacc[4] = {};
#pragma unroll
  for (int kt = 0; kt < 8; ++kt) {
    int prow = lane & 15;
    bf16x8 pf = *(const bf16x8*)(Pb + prow * 512 +
                                 ((2 * (kt * 32 + ((lane >> 4) << 3))) ^ ((prow & 7) << 4)));
#pragma unroll
    for (int nt = 0; nt < 4; ++nt) {
      int vd = nt * 16 + (lane & 15);
      int vk = kt * 32 + ((lane >> 4) << 3);
      int key = (((vd & 7) ^ ((vd >> 3) & 7)) & 7) << 4;
      bf16x8 vf = *(const bf16x8*)((char*)ldsV + vd * 512 + ((2 * vk) ^ key));
      oacc[nt] = __builtin_amdgcn_mfma_f32_16x16x32_bf16(pf, vf, oacc[nt], 0, 0, 0);
    }
  }

  size_t obase = ((size_t)(b * 4096 + blk * 256 + quarter * 64 + w * 16)) * 1024 + h * 64;
#pragma unroll
  for (int nt = 0; nt < 4; ++nt)
#pragma unroll
    for (int reg = 0; reg < 4; ++reg) {
      int orow = ((lane >> 4) << 2) + reg;
      int od = nt * 16 + (lane & 15);
      o[obase + (size_t)orow * 1024 + od] = f2bf(oacc[nt][reg] * rden[reg]);
    }
}

// ---------------- launch ----------------

extern "C" void kernel_launch(void* const* d_in, const int* in_sizes, int n_in,
                              void* d_out, int out_size, void* d_ws, size_t ws_size,
                              hipStream_t stream) {
  (void)in_sizes; (void)n_in; (void)out_size; (void)ws_size;
  const float* x = (const float*)d_in[0];
  const float* Wqkv = (const float*)d_in[1];
  const float* bqkv = (const float*)d_in[2];
  const float* Wout = (const float*)d_in[3];
  const float* bout = (const float*)d_in[4];
  float* out = (float*)d_out;

  char* ws = (char*)d_ws;
  u16* xb    = (u16*)(ws + 0);
  u16* wqkvT = (u16*)(ws + 33554432);
  u16* woT   = (u16*)(ws + 39845888);
  u16* qkv   = (u16*)(ws + 41943040);
  u16* ob    = (u16*)(ws + 142606336);

  hipFuncSetAttribute(reinterpret_cast<const void*>(&k_gemm8<1, 1024>),
                      hipFuncAttributeMaxDynamicSharedMemorySize, 131072);
  hipFuncSetAttribute(reinterpret_cast<const void*>(&k_gemm8<0, 1024>),
                      hipFuncAttributeMaxDynamicSharedMemorySize, 131072);

  k_cvt_bf16<<<8192, 256, 0, stream>>>(x, xb, 16384 * 1024 / 8);
  k_transpose_cvt<<<dim3(96, 32), dim3(32, 8), 0, stream>>>(Wqkv, wqkvT, 1024, 3072);
  k_transpose_cvt<<<dim3(32, 32), dim3(32, 8), 0, stream>>>(Wout, woT, 1024, 1024);

  // qkv = x @ Wqkv + bqkv  (bf16 out): 64x12 = 768 tiles
  k_gemm8<1, 1024><<<768, 512, 131072, stream>>>(xb, wqkvT, bqkv, qkv, 16384, 3072);

  // block-diagonal attention
  k_attn<<<4096, 256, 0, stream>>>(qkv, ob);

  // out = o @ Wout + bout  (fp32 out): 64x4 = 256 tiles
  k_gemm8<0, 1024><<<256, 512, 131072, stream>>>(ob, woT, bout, out, 16384, 1024);
}

// Round 3
// 229.360 us; speedup vs baseline: 1.2818x; 1.0496x over previous
//
#include <hip/hip_runtime.h>

typedef unsigned int u32;
typedef unsigned short u16;
typedef short bf16x8 __attribute__((ext_vector_type(8)));
typedef u16 u16x8 __attribute__((ext_vector_type(8)));
typedef float f32x4 __attribute__((ext_vector_type(4)));

// ---------------- helpers ----------------

__device__ __forceinline__ u16 f2bf(float f) {
  unsigned u = __float_as_uint(f);
  u += 0x7FFFu + ((u >> 16) & 1u);   // RNE
  return (u16)(u >> 16);
}

typedef const void __attribute__((address_space(1)))* gas_p;
typedef void __attribute__((address_space(3)))* las_p;

__device__ __forceinline__ void async_ld16(const void* g, void* l) {
  __builtin_amdgcn_global_load_lds((gas_p)g, (las_p)l, 16, 0, 0);
}

// ---------------- convert x -> bf16 ----------------

__global__ __launch_bounds__(256) void k_cvt_bf16(const float* __restrict__ in,
                                                  u16* __restrict__ out, int n8) {
  int i = blockIdx.x * 256 + threadIdx.x;
  if (i >= n8) return;
  const float4* p = (const float4*)in + (size_t)i * 2;
  float4 a = p[0], b = p[1];
  u16x8 o;
  o[0] = f2bf(a.x); o[1] = f2bf(a.y); o[2] = f2bf(a.z); o[3] = f2bf(a.w);
  o[4] = f2bf(b.x); o[5] = f2bf(b.y); o[6] = f2bf(b.z); o[7] = f2bf(b.w);
  *((u16x8*)out + i) = o;
}

// ---------------- transpose + convert W[K][N] -> Wt[N][K] bf16 ----------------

__global__ __launch_bounds__(256) void k_transpose_cvt(const float* __restrict__ in,
                                                       u16* __restrict__ out,
                                                       int R, int Ncols) {
  __shared__ u16 t[32][33];
  int tx = threadIdx.x, ty = threadIdx.y;
  int c0 = blockIdx.x * 32, r0 = blockIdx.y * 32;
#pragma unroll
  for (int j = 0; j < 32; j += 8)
    t[ty + j][tx] = f2bf(in[(size_t)(r0 + ty + j) * Ncols + c0 + tx]);
  __syncthreads();
#pragma unroll
  for (int j = 0; j < 32; j += 8)
    out[(size_t)(c0 + ty + j) * R + r0 + tx] = t[tx][ty + j];
}

// ---------------- 256^2 8-phase bf16 GEMM, persistent ----------------

#define MFMA2(m, n)                                                                   \
  acc[m][n] = __builtin_amdgcn_mfma_f32_16x16x32_bf16(a[m][0], b[n][0], acc[m][n], 0, 0, 0); \
  acc[m][n] = __builtin_amdgcn_mfma_f32_16x16x32_bf16(a[m][1], b[n][1], acc[m][n], 0, 0, 0);

#define STAGE_A(h_, T_, dd_) do {                                          \
    const u16* g_ = pAg + (size_t)(h_) * 128 * KK + (size_t)(T_) * 64;     \
    u16* s_ = lds + (dd_) * 16384 + ((h_) * 128 + w * 16) * 64;            \
    async_ld16(g_, s_);                                                    \
    async_ld16(g_ + 8 * (size_t)KK, s_ + 512);                             \
  } while (0)

#define STAGE_B(h_, T_, dd_) do {                                          \
    const u16* g_ = pBg + (size_t)(h_) * 128 * KK + (size_t)(T_) * 64;     \
    u16* s_ = lds + 32768 + (dd_) * 16384 + ((h_) * 128 + w * 16) * 64;    \
    async_ld16(g_, s_);                                                    \
    async_ld16(g_ + 8 * (size_t)KK, s_ + 512);                             \
  } while (0)

#define TB(k_, d_)                                                              \
  {                                                                             \
    const int doA = (d_) * 16384, doB = 32768 + (d_) * 16384;                   \
    _Pragma("unroll") for (int f = 0; f < 4; ++f) {                             \
      a[f][0] = *(const bf16x8*)(lds + doA + rAoff + f * 1024 + c0);            \
      a[f][1] = *(const bf16x8*)(lds + doA + rAoff + f * 1024 + c1);            \
    }                                                                           \
    _Pragma("unroll") for (int f = 0; f < 2; ++f) {                             \
      b[f][0] = *(const bf16x8*)(lds + doB + rBoff + f * 1024 + c0);            \
      b[f][1] = *(const bf16x8*)(lds + doB + rBoff + f * 1024 + c1);            \
    }                                                                           \
    if ((k_) + 1 < NT) STAGE_B(0, (k_) + 1, (d_) ^ 1);                          \
    asm volatile("s_waitcnt lgkmcnt(8)");                                       \
    __builtin_amdgcn_s_barrier();                                               \
    asm volatile("s_waitcnt lgkmcnt(0)");                                       \
    __builtin_amdgcn_s_setprio(1);                                              \
    MFMA2(0, 0); MFMA2(1, 0); MFMA2(2, 0); MFMA2(3, 0);                         \
    MFMA2(0, 1); MFMA2(1, 1); MFMA2(2, 1); MFMA2(3, 1);                         \
    __builtin_amdgcn_s_setprio(0);                                              \
    __builtin_amdgcn_s_barrier();                                               \
    _Pragma("unroll") for (int f = 4; f < 8; ++f) {                             \
      a[f][0] = *(const bf16x8*)(lds + doA + rAoff + f * 1024 + c0);            \
      a[f][1] = *(const bf16x8*)(lds + doA + rAoff + f * 1024 + c1);            \
    }                                                                           \
    if ((k_) + 1 < NT) STAGE_B(1, (k_) + 1, (d_) ^ 1);                          \
    __builtin_amdgcn_s_barrier();                                               \
    asm volatile("s_waitcnt lgkmcnt(0)");                                       \
    __builtin_amdgcn_s_setprio(1);                                              \
    MFMA2(4, 0); MFMA2(5, 0); MFMA2(6, 0); MFMA2(7, 0);                         \
    MFMA2(4, 1); MFMA2(5, 1); MFMA2(6, 1); MFMA2(7, 1);                         \
    __builtin_amdgcn_s_setprio(0);                                              \
    __builtin_amdgcn_s_barrier();                                               \
    _Pragma("unroll") for (int f = 2; f < 4; ++f) {                             \
      b[f][0] = *(const bf16x8*)(lds + doB + rBoff + f * 1024 + c0);            \
      b[f][1] = *(const bf16x8*)(lds + doB + rBoff + f * 1024 + c1);            \
    }                                                                           \
    if ((k_) + 2 < NT) STAGE_A(0, (k_) + 2, (d_));                              \
    __builtin_amdgcn_s_barrier();                                               \
    asm volatile("s_waitcnt lgkmcnt(0)");                                       \
    __builtin_amdgcn_s_setprio(1);                                              \
    MFMA2(4, 2); MFMA2(5, 2); MFMA2(6, 2); MFMA2(7, 2);                         \
    MFMA2(4, 3); MFMA2(5, 3); MFMA2(6, 3); MFMA2(7, 3);                         \
    __builtin_amdgcn_s_setprio(0);                                              \
    __builtin_amdgcn_s_barrier();                                               \
    if ((k_) + 2 < NT) STAGE_A(1, (k_) + 2, (d_));                              \
    __builtin_amdgcn_s_setprio(1);                                              \
    MFMA2(0, 2); MFMA2(1, 2); MFMA2(2, 2); MFMA2(3, 2);                         \
    MFMA2(0, 3); MFMA2(1, 3); MFMA2(2, 3); MFMA2(3, 3);                         \
    __builtin_amdgcn_s_setprio(0);                                              \
    if ((k_) < NT - 2) { asm volatile("s_waitcnt vmcnt(4)"); }                  \
    else               { asm volatile("s_waitcnt vmcnt(0)"); }                  \
    __builtin_amdgcn_s_barrier();                                               \
  }

#define EPI(PM0, PN0) do {                                                      \
    int ccol0 = (PN0) + wn * 64 + (lane & 15);                                  \
    float bv0 = bias[ccol0], bv1 = bias[ccol0 + 16];                            \
    float bv2 = bias[ccol0 + 32], bv3 = bias[ccol0 + 48];                       \
    size_t crow0 = (size_t)((PM0) + wm * 128 + ((lane >> 4) << 2));             \
    _Pragma("unroll") for (int m = 0; m < 8; ++m)                               \
    _Pragma("unroll") for (int reg = 0; reg < 4; ++reg) {                       \
      size_t ro = (crow0 + m * 16 + reg) * (size_t)N + ccol0;                   \
      float v0 = acc[m][0][reg] + bv0, v1 = acc[m][1][reg] + bv1;               \
      float v2 = acc[m][2][reg] + bv2, v3 = acc[m][3][reg] + bv3;               \
      if (OUT_BF16) {                                                           \
        ((u16*)Cout)[ro] = f2bf(v0); ((u16*)Cout)[ro + 16] = f2bf(v1);          \
        ((u16*)Cout)[ro + 32] = f2bf(v2); ((u16*)Cout)[ro + 48] = f2bf(v3);     \
      } else {                                                                  \
        ((float*)Cout)[ro] = v0; ((float*)Cout)[ro + 16] = v1;                  \
        ((float*)Cout)[ro + 32] = v2; ((float*)Cout)[ro + 48] = v3;             \
      }                                                                         \
    }                                                                           \
  } while (0)

template <int OUT_BF16, int KK>
__global__ __launch_bounds__(512, 2) void k_gemm8(const u16* __restrict__ A,
                                                  const u16* __restrict__ Bt,
                                                  const float* __restrict__ bias,
                                                  void* __restrict__ Cout,
                                                  int M, int N) {
  extern __shared__ u16 lds[];
  const int NT = KK / 64;

  int nbn = N >> 8, nbm = M >> 8, nwg = nbm * nbn;
  int tid = threadIdx.x;
  int w = tid >> 6, lane = tid & 63;
  int wm = w >> 2, wn = w & 3;

  int rAoff = (wm * 128 + (lane & 15)) << 6;
  int rBoff = (wn * 64 + (lane & 15)) << 6;
  int hi8 = (lane >> 4) << 3, key8 = (lane & 7) << 3;
  int c0 = hi8 ^ key8;
  int c1 = (32 | hi8) ^ key8;
  int rowoff = w * 16 + (lane >> 3);
  int soff = ((lane & 7) ^ (lane >> 3)) << 3;

  bf16x8 a[8][2], b[4][2];
  f32x4 acc[8][4];
  const u16 *pAg = A, *pBg = Bt;
  int pm0 = 0, pn0 = 0;

  for (int t = blockIdx.x; t < nwg; t += gridDim.x) {
    int q = nwg >> 3, r = nwg & 7, x = t & 7, loc = t >> 3;
    int swz = (x < r ? x * (q + 1) : r * (q + 1) + (x - r) * q) + loc;
    int mi = swz / nbn, ni = swz % nbn;
    int m0 = mi << 8, n0 = ni << 8;

    // previous tile's epilogue stores FIRST (so vmcnt(4) below waits only them
    // + 8 of the 12 new loads, leaving tile1-A in flight)
    if (t != (int)blockIdx.x) EPI(pm0, pn0);

    pAg = A + (size_t)(m0 + rowoff) * KK + soff;
    pBg = Bt + (size_t)(n0 + rowoff) * KK + soff;
    STAGE_A(0, 0, 0); STAGE_A(1, 0, 0); STAGE_B(0, 0, 0); STAGE_B(1, 0, 0);
    STAGE_A(0, 1, 1); STAGE_A(1, 1, 1);
    asm volatile("s_waitcnt vmcnt(4)");
    __builtin_amdgcn_s_barrier();

#pragma unroll
    for (int m = 0; m < 8; ++m)
#pragma unroll
      for (int n = 0; n < 4; ++n) acc[m][n] = (f32x4){0.f, 0.f, 0.f, 0.f};

    for (int k = 0; k < NT; k += 2) {
      TB(k, 0);
      TB(k + 1, 1);
    }
    pm0 = m0; pn0 = n0;
  }
  EPI(pm0, pn0);
}

// ---------------- block-diagonal attention v2 ----------------
// 1024 WGs (b,h,blk), 512 threads = 8 waves, 32 q-rows/wave (2 sets of 16).
// Swapped QK^T (S^T = mfma(K, Q)); P kept in registers via cvt_pk + shfl
// redistribution; K via global_load_lds (pre-swizzled source); V^T scalar-staged.

__global__ __launch_bounds__(512, 2) void k_attn2(const u16* __restrict__ qkv,
                                                  u16* __restrict__ o) {
  __shared__ u16 ldsK[256 * 64];   // [t][granule^ (t&7)] swizzled
  __shared__ u16 ldsV[64 * 256];   // V^T [d][t] swizzled

  int bid = blockIdx.x;
  int g = ((bid & 7) << 7) | (bid >> 3);   // nwg = 1024, bijective XCD swizzle
  int blk = g & 15, h = (g >> 4) & 15, b = g >> 8;

  int tid = threadIdx.x;
  int w = tid >> 6, lane = tid & 63;
  int hgrp = lane >> 4;
  size_t rowb = ((size_t)(b * 4096 + blk * 256)) * 3072 + (size_t)h * 192;

  // Q fragments (B-operand; col=lane&15=q-in-set, k=d contiguous at hgrp*8)
  int qbase = w * 32;
  const u16* qp0 = qkv + rowb + (size_t)(qbase + (lane & 15)) * 3072 + hgrp * 8;
  const u16* qp1 = qp0 + (size_t)16 * 3072;
  bf16x8 qf00 = *(const bf16x8*)(qp0);
  bf16x8 qf01 = *(const bf16x8*)(qp0 + 32);
  bf16x8 qf10 = *(const bf16x8*)(qp1);
  bf16x8 qf11 = *(const bf16x8*)(qp1 + 32);

  // ---- stage K (async, pre-swizzled source) + V^T (scalar transpose) ----
#pragma unroll
  for (int it = 0; it < 4; ++it) {
    int trow = it * 64 + (tid >> 3);
    // K: wave-linear LDS dest; source granule = (lane&7) ^ (lane>>3)
    const u16* ksrc = qkv + rowb + (size_t)trow * 3072 + 64 +
                      (((lane & 7) ^ (lane >> 3)) << 3);
    async_ld16(ksrc, ldsK + (it * 64 + w * 8) * 64);
    // V: load row, scatter transposed
    int d0 = (tid & 7) << 3;
    uint4 vv = *(const uint4*)(qkv + rowb + (size_t)trow * 3072 + 128 + d0);
    union { uint4 v; u16 s[8]; } uv;
    uv.v = vv;
#pragma unroll
    for (int j = 0; j < 8; ++j) {
      int d = d0 + j;
      int key = (((d & 7) ^ ((d >> 3) & 7)) & 7) << 4;
      *(u16*)((char*)ldsV + d * 512 + ((2 * trow) ^ key)) = uv.s[j];
    }
  }
  __syncthreads();

  // ---- S^T = K Q : acc[ct] rows t=ct*16+4*h'+reg, col q=lane&15 ----
  f32x4 acc0[16] = {}, acc1[16] = {};
  int cb = hgrp << 4;
#pragma unroll
  for (int ct = 0; ct < 16; ++ct) {
    int krow = ct * 16 + (lane & 15);
    const char* kb = (const char*)ldsK + krow * 128;
    int key = (krow & 7) << 4;
    bf16x8 k0 = *(const bf16x8*)(kb + (cb ^ key));
    bf16x8 k1 = *(const bf16x8*)(kb + ((64 + cb) ^ key));
    acc0[ct] = __builtin_amdgcn_mfma_f32_16x16x32_bf16(k0, qf00, acc0[ct], 0, 0, 0);
    acc0[ct] = __builtin_amdgcn_mfma_f32_16x16x32_bf16(k1, qf01, acc0[ct], 0, 0, 0);
    acc1[ct] = __builtin_amdgcn_mfma_f32_16x16x32_bf16(k0, qf10, acc1[ct], 0, 0, 0);
    acc1[ct] = __builtin_amdgcn_mfma_f32_16x16x32_bf16(k1, qf11, acc1[ct], 0, 0, 0);
  }

  // ---- softmax (reduction over t is in-lane 64 values + xor16/xor32) ----
  const float SC = 0.125f * 1.44269504f;
  float rden0, rden1;
  {
    float mx = -1e30f;
#pragma unroll
    for (int ct = 0; ct < 16; ++ct)
#pragma unroll
      for (int rg = 0; rg < 4; ++rg) mx = fmaxf(mx, acc0[ct][rg]);
    mx = fmaxf(mx, __shfl_xor(mx, 16));
    mx = fmaxf(mx, __shfl_xor(mx, 32));
    float s = 0.f;
#pragma unroll
    for (int ct = 0; ct < 16; ++ct)
#pragma unroll
      for (int rg = 0; rg < 4; ++rg) {
        float p = exp2f((acc0[ct][rg] - mx) * SC);
        acc0[ct][rg] = p;
        s += p;
      }
    s += __shfl_xor(s, 16);
    s += __shfl_xor(s, 32);
    rden0 = 1.f / s;
  }
  {
    float mx = -1e30f;
#pragma unroll
    for (int ct = 0; ct < 16; ++ct)
#pragma unroll
      for (int rg = 0; rg < 4; ++rg) mx = fmaxf(mx, acc1[ct][rg]);
    mx = fmaxf(mx, __shfl_xor(mx, 16));
    mx = fmaxf(mx, __shfl_xor(mx, 32));
    float s = 0.f;
#pragma unroll
    for (int ct = 0; ct < 16; ++ct)
#pragma unroll
      for (int rg = 0; rg < 4; ++rg) {
        float p = exp2f((acc1[ct][rg] - mx) * SC);
        acc1[ct][rg] = p;
        s += p;
      }
    s += __shfl_xor(s, 16);
    s += __shfl_xor(s, 32);
    rden1 = 1.f / s;
  }

  // ---- P^T(acc) -> PV A-fragments via cvt_pk + 4-lane-group shfl ----
  // target lane h, elem j:  P[q][t=32kt+8h+j]; source: ct=2kt+(h>=2),
  // h'=2(h&1)+(j>=4), reg=j&3.  s1 = q+32(h&1), s2 = s1+16, sel on h<2.
  int s1 = (lane & 15) + ((lane >> 4) & 1) * 32;
  int s2 = s1 + 16;
  bool lo = (lane < 32);
  bf16x8 pa0[8], pa1[8];
#define PCONV(ACC, PA)                                                      \
  _Pragma("unroll") for (int kt = 0; kt < 8; ++kt) {                        \
    u32 wA0, wB0, wA1, wB1;                                                 \
    asm("v_cvt_pk_bf16_f32 %0, %1, %2" : "=v"(wA0)                          \
        : "v"(ACC[2 * kt][0]), "v"(ACC[2 * kt][1]));                        \
    asm("v_cvt_pk_bf16_f32 %0, %1, %2" : "=v"(wB0)                          \
        : "v"(ACC[2 * kt][2]), "v"(ACC[2 * kt][3]));                        \
    asm("v_cvt_pk_bf16_f32 %0, %1, %2" : "=v"(wA1)                          \
        : "v"(ACC[2 * kt + 1][0]), "v"(ACC[2 * kt + 1][1]));                \
    asm("v_cvt_pk_bf16_f32 %0, %1, %2" : "=v"(wB1)                          \
        : "v"(ACC[2 * kt + 1][2]), "v"(ACC[2 * kt + 1][3]));                \
    u32 t0a = (u32)__shfl((int)wA0, s1), t0b = (u32)__shfl((int)wA1, s1);   \
    u32 t1a = (u32)__shfl((int)wB0, s1), t1b = (u32)__shfl((int)wB1, s1);   \
    u32 t2a = (u32)__shfl((int)wA0, s2), t2b = (u32)__shfl((int)wA1, s2);   \
    u32 t3a = (u32)__shfl((int)wB0, s2), t3b = (u32)__shfl((int)wB1, s2);   \
    union { u32 w[4]; bf16x8 v; } pu;                                       \
    pu.w[0] = lo ? t0a : t0b;                                               \
    pu.w[1] = lo ? t1a : t1b;                                               \
    pu.w[2] = lo ? t2a : t2b;                                               \
    pu.w[3] = lo ? t3a : t3b;                                               \
    PA[kt] = pu.v;                                                          \
  }
  PCONV(acc0, pa0)
  PCONV(acc1, pa1)
#undef PCONV

  // ---- O = P V ----
  f32x4 oa0[4] = {}, oa1[4] = {};
#pragma unroll
  for (int kt = 0; kt < 8; ++kt) {
    int vkb = 2 * (kt * 32 + hgrp * 8);
#pragma unroll
    for (int nt = 0; nt < 4; ++nt) {
      int vd = nt * 16 + (lane & 15);
      int key = (((vd & 7) ^ ((vd >> 3) & 7)) & 7) << 4;
      bf16x8 vf = *(const bf16x8*)((char*)ldsV + vd * 512 + (vkb ^ key));
      oa0[nt] = __builtin_amdgcn_mfma_f32_16x16x32_bf16(pa0[kt], vf, oa0[nt], 0, 0, 0);
      oa1[nt] = __builtin_amdgcn_mfma_f32_16x16x32_bf16(pa1[kt], vf, oa1[nt], 0, 0, 0);
    }
  }

  // ---- epilogue: rows q = set*16 + 4*hgrp + reg, col d = nt*16 + lane&15 ----
  float rd0[4], rd1[4];
#pragma unroll
  for (int rg = 0; rg < 4; ++rg) {
    rd0[rg] = __shfl(rden0, 4 * hgrp + rg, 16);
    rd1[rg] = __shfl(rden1, 4 * hgrp + rg, 16);
  }
  size_t ob = ((size_t)(b * 4096 + blk * 256 + qbase)) * 1024 + (size_t)h * 64;
#pragma unroll
  for (int nt = 0; nt < 4; ++nt)
#pragma unroll
    for (int rg = 0; rg < 4; ++rg) {
      int col = nt * 16 + (lane & 15);
      o[ob + (size_t)(4 * hgrp + rg) * 1024 + col] = f2bf(oa0[nt][rg] * rd0[rg]);
      o[ob + (size_t)(16 + 4 * hgrp + rg) * 1024 + col] = f2bf(oa1[nt][rg] * rd1[rg]);
    }
}

// ---------------- launch ----------------

extern "C" void kernel_launch(void* const* d_in, const int* in_sizes, int n_in,
                              void* d_out, int out_size, void* d_ws, size_t ws_size,
                              hipStream_t stream) {
  (void)in_sizes; (void)n_in; (void)out_size; (void)ws_size;
  const float* x = (const float*)d_in[0];
  const float* Wqkv = (const float*)d_in[1];
  const float* bqkv = (const float*)d_in[2];
  const float* Wout = (const float*)d_in[3];
  const float* bout = (const float*)d_in[4];
  float* out = (float*)d_out;

  char* ws = (char*)d_ws;
  u16* xb    = (u16*)(ws + 0);
  u16* wqkvT = (u16*)(ws + 33554432);
  u16* woT   = (u16*)(ws + 39845888);
  u16* qkv   = (u16*)(ws + 41943040);
  u16* ob    = (u16*)(ws + 142606336);

  hipFuncSetAttribute(reinterpret_cast<const void*>(&k_gemm8<1, 1024>),
                      hipFuncAttributeMaxDynamicSharedMemorySize, 131072);
  hipFuncSetAttribute(reinterpret_cast<const void*>(&k_gemm8<0, 1024>),
                      hipFuncAttributeMaxDynamicSharedMemorySize, 131072);

  k_cvt_bf16<<<8192, 256, 0, stream>>>(x, xb, 16384 * 1024 / 8);
  k_transpose_cvt<<<dim3(96, 32), dim3(32, 8), 0, stream>>>(Wqkv, wqkvT, 1024, 3072);
  k_transpose_cvt<<<dim3(32, 32), dim3(32, 8), 0, stream>>>(Wout, woT, 1024, 1024);

  // qkv = x @ Wqkv + bqkv (bf16 out): 768 tiles, persistent over 256 WGs
  k_gemm8<1, 1024><<<256, 512, 131072, stream>>>(xb, wqkvT, bqkv, qkv, 16384, 3072);

  // block-diagonal attention: one WG per (b,h,blk)
  k_attn2<<<1024, 512, 0, stream>>>(qkv, ob);

  // out = o @ Wout + bout (fp32 out): 256 tiles
  k_gemm8<0, 1024><<<256, 512, 131072, stream>>>(ob, woT, bout, out, 16384, 1024);
}

// Round 4
// 228.530 us; speedup vs baseline: 1.2865x; 1.0036x over previous
//
#include <hip/hip_runtime.h>

typedef unsigned int u32;
typedef unsigned short u16;
typedef short bf16x8 __attribute__((ext_vector_type(8)));
typedef u16 u16x8 __attribute__((ext_vector_type(8)));
typedef float f32x4 __attribute__((ext_vector_type(4)));

// ---------------- helpers ----------------

__device__ __forceinline__ u16 f2bf(float f) {
  unsigned u = __float_as_uint(f);
  u += 0x7FFFu + ((u >> 16) & 1u);   // RNE
  return (u16)(u >> 16);
}

typedef const void __attribute__((address_space(1)))* gas_p;
typedef void __attribute__((address_space(3)))* las_p;

__device__ __forceinline__ void async_ld16(const void* g, void* l) {
  __builtin_amdgcn_global_load_lds((gas_p)g, (las_p)l, 16, 0, 0);
}

// ---------------- convert x -> bf16 ----------------

__global__ __launch_bounds__(256) void k_cvt_bf16(const float* __restrict__ in,
                                                  u16* __restrict__ out, int n8) {
  int i = blockIdx.x * 256 + threadIdx.x;
  if (i >= n8) return;
  const float4* p = (const float4*)in + (size_t)i * 2;
  float4 a = p[0], b = p[1];
  u16x8 o;
  o[0] = f2bf(a.x); o[1] = f2bf(a.y); o[2] = f2bf(a.z); o[3] = f2bf(a.w);
  o[4] = f2bf(b.x); o[5] = f2bf(b.y); o[6] = f2bf(b.z); o[7] = f2bf(b.w);
  *((u16x8*)out + i) = o;
}

// ---------------- transpose + convert W[K][N] -> Wt[N][K] bf16 ----------------

__global__ __launch_bounds__(256) void k_transpose_cvt(const float* __restrict__ in,
                                                       u16* __restrict__ out,
                                                       int R, int Ncols) {
  __shared__ u16 t[32][33];
  int tx = threadIdx.x, ty = threadIdx.y;
  int c0 = blockIdx.x * 32, r0 = blockIdx.y * 32;
#pragma unroll
  for (int j = 0; j < 32; j += 8)
    t[ty + j][tx] = f2bf(in[(size_t)(r0 + ty + j) * Ncols + c0 + tx]);
  __syncthreads();
#pragma unroll
  for (int j = 0; j < 32; j += 8)
    out[(size_t)(c0 + ty + j) * R + r0 + tx] = t[tx][ty + j];
}

// ---------------- 256^2 8-phase bf16 GEMM, cross-tile pipelined ----------------

#define STAGE_A2(h_, src_, dd_) do {                                       \
    const u16* g_ = (src_) + (size_t)(h_) * 128 * KK;                      \
    u16* s_ = lds + (dd_) * 16384 + (((h_) * 128 + w * 16) << 6);          \
    async_ld16(g_, s_);                                                    \
    async_ld16(g_ + 8 * (size_t)KK, s_ + 512);                             \
  } while (0)

#define STAGE_B2(h_, src_, dd_) do {                                       \
    const u16* g_ = (src_) + (size_t)(h_) * 128 * KK;                      \
    u16* s_ = lds + 32768 + (dd_) * 16384 + (((h_) * 128 + w * 16) << 6);  \
    async_ld16(g_, s_);                                                    \
    async_ld16(g_ + 8 * (size_t)KK, s_ + 512);                             \
  } while (0)

// 16 MFMA: ks-outer -> 8 independent MFMAs between dependent pairs
#define MQUAD(M0, N0)                                                      \
    _Pragma("unroll") for (int ks = 0; ks < 2; ++ks)                       \
    _Pragma("unroll") for (int mm = 0; mm < 4; ++mm)                       \
    _Pragma("unroll") for (int nn = 0; nn < 2; ++nn)                       \
      acc[(M0) + mm][(N0) + nn] = __builtin_amdgcn_mfma_f32_16x16x32_bf16( \
          a[(M0) + mm][ks], b[(N0) + nn][ks], acc[(M0) + mm][(N0) + nn], 0, 0, 0);

#define TBX(d_, bS_, aS_)                                                  \
  {                                                                        \
    const int doA = (d_) * 16384, doB = 32768 + (d_) * 16384;              \
    _Pragma("unroll") for (int f = 0; f < 4; ++f) {                        \
      a[f][0] = *(const bf16x8*)(lds + doA + rAoff + f * 1024 + c0);       \
      a[f][1] = *(const bf16x8*)(lds + doA + rAoff + f * 1024 + c1);       \
    }                                                                      \
    _Pragma("unroll") for (int f = 0; f < 2; ++f) {                        \
      b[f][0] = *(const bf16x8*)(lds + doB + rBoff + f * 1024 + c0);       \
      b[f][1] = *(const bf16x8*)(lds + doB + rBoff + f * 1024 + c1);       \
    }                                                                      \
    STAGE_B2(0, bS_, (d_) ^ 1);                                            \
    asm volatile("s_waitcnt lgkmcnt(8)");                                  \
    __builtin_amdgcn_s_barrier();                                          \
    asm volatile("s_waitcnt lgkmcnt(0)");                                  \
    __builtin_amdgcn_s_setprio(1);                                         \
    MQUAD(0, 0)                                                            \
    __builtin_amdgcn_s_setprio(0);                                         \
    __builtin_amdgcn_s_barrier();                                          \
    _Pragma("unroll") for (int f = 4; f < 8; ++f) {                        \
      a[f][0] = *(const bf16x8*)(lds + doA + rAoff + f * 1024 + c0);       \
      a[f][1] = *(const bf16x8*)(lds + doA + rAoff + f * 1024 + c1);       \
    }                                                                      \
    STAGE_B2(1, bS_, (d_) ^ 1);                                            \
    __builtin_amdgcn_s_barrier();                                          \
    asm volatile("s_waitcnt lgkmcnt(0)");                                  \
    __builtin_amdgcn_s_setprio(1);                                         \
    MQUAD(4, 0)                                                            \
    __builtin_amdgcn_s_setprio(0);                                         \
    __builtin_amdgcn_s_barrier();                                          \
    _Pragma("unroll") for (int f = 2; f < 4; ++f) {                        \
      b[f][0] = *(const bf16x8*)(lds + doB + rBoff + f * 1024 + c0);       \
      b[f][1] = *(const bf16x8*)(lds + doB + rBoff + f * 1024 + c1);       \
    }                                                                      \
    STAGE_A2(0, aS_, (d_));                                                \
    __builtin_amdgcn_s_barrier();                                          \
    asm volatile("s_waitcnt lgkmcnt(0)");                                  \
    __builtin_amdgcn_s_setprio(1);                                         \
    MQUAD(4, 2)                                                            \
    __builtin_amdgcn_s_setprio(0);                                         \
    __builtin_amdgcn_s_barrier();                                          \
    STAGE_A2(1, aS_, (d_));                                                \
    __builtin_amdgcn_s_setprio(1);                                         \
    MQUAD(0, 2)                                                            \
    __builtin_amdgcn_s_setprio(0);                                         \
    asm volatile("s_waitcnt vmcnt(4)");                                    \
    __builtin_amdgcn_s_barrier();                                          \
  }

#define EPI(PM0, PN0) do {                                                      \
    int ccol0 = (PN0) + wn * 64 + (lane & 15);                                  \
    float bv0 = bias[ccol0], bv1 = bias[ccol0 + 16];                            \
    float bv2 = bias[ccol0 + 32], bv3 = bias[ccol0 + 48];                       \
    size_t crow0 = (size_t)((PM0) + wm * 128 + ((lane >> 4) << 2));             \
    _Pragma("unroll") for (int m = 0; m < 8; ++m)                               \
    _Pragma("unroll") for (int reg = 0; reg < 4; ++reg) {                       \
      size_t ro = (crow0 + m * 16 + reg) * (size_t)N + ccol0;                   \
      float v0 = acc[m][0][reg] + bv0, v1 = acc[m][1][reg] + bv1;               \
      float v2 = acc[m][2][reg] + bv2, v3 = acc[m][3][reg] + bv3;               \
      if (OUT_BF16) {                                                           \
        ((u16*)Cout)[ro] = f2bf(v0); ((u16*)Cout)[ro + 16] = f2bf(v1);          \
        ((u16*)Cout)[ro + 32] = f2bf(v2); ((u16*)Cout)[ro + 48] = f2bf(v3);     \
      } else {                                                                  \
        ((float*)Cout)[ro] = v0; ((float*)Cout)[ro + 16] = v1;                  \
        ((float*)Cout)[ro + 32] = v2; ((float*)Cout)[ro + 48] = v3;             \
      }                                                                         \
    }                                                                           \
  } while (0)

#define TILE_COORD(tt, mm0, nn0) do {                                           \
    int q_ = nwg >> 3, r_ = nwg & 7, x_ = (tt) & 7, loc_ = (tt) >> 3;           \
    int swz_ = (x_ < r_ ? x_ * (q_ + 1) : r_ * (q_ + 1) + (x_ - r_) * q_) + loc_;\
    mm0 = (swz_ / nbn) << 8; nn0 = (swz_ % nbn) << 8;                           \
  } while (0)

#define ZERO_ACC do {                                                           \
    _Pragma("unroll") for (int m = 0; m < 8; ++m)                               \
    _Pragma("unroll") for (int n = 0; n < 4; ++n)                               \
      acc[m][n] = (f32x4){0.f, 0.f, 0.f, 0.f};                                  \
  } while (0)

template <int OUT_BF16, int KK>
__global__ __launch_bounds__(512, 2) void k_gemm8(const u16* __restrict__ A,
                                                  const u16* __restrict__ Bt,
                                                  const float* __restrict__ bias,
                                                  void* __restrict__ Cout,
                                                  int M, int N) {
  extern __shared__ u16 lds[];
  const int NT = KK / 64;

  int nbn = N >> 8, nbm = M >> 8, nwg = nbm * nbn;
  int tid = threadIdx.x;
  int w = tid >> 6, lane = tid & 63;
  int wm = w >> 2, wn = w & 3;

  int rAoff = (wm * 128 + (lane & 15)) << 6;
  int rBoff = (wn * 64 + (lane & 15)) << 6;
  int hi8 = (lane >> 4) << 3, key8 = (lane & 7) << 3;
  int c0 = hi8 ^ key8;
  int c1 = (32 | hi8) ^ key8;
  int rowoff = w * 16 + (lane >> 3);
  int soff = ((lane & 7) ^ (lane >> 3)) << 3;

  bf16x8 a[8][2], b[4][2];
  f32x4 acc[8][4];

  int t = blockIdx.x;
  int m0, n0;
  TILE_COORD(t, m0, n0);
  const u16* pAg = A + (size_t)(m0 + rowoff) * KK + soff;
  const u16* pBg = Bt + (size_t)(n0 + rowoff) * KK + soff;

  // prologue: tile0 T0 fully + T1 A-halves; leave T1-A in flight
  STAGE_A2(0, pAg, 0); STAGE_A2(1, pAg, 0);
  STAGE_B2(0, pBg, 0); STAGE_B2(1, pBg, 0);
  STAGE_A2(0, pAg + 64, 1); STAGE_A2(1, pAg + 64, 1);
  asm volatile("s_waitcnt vmcnt(4)");
  __builtin_amdgcn_s_barrier();
  ZERO_ACC;

  for (;;) {
    int tn = t + gridDim.x;
    bool last = tn >= nwg;
    const u16 *pAgN, *pBgN;
    int m0N = m0, n0N = n0;
    if (last) {                 // dummy: re-stage own tile start (L2-hot)
      pAgN = pAg; pBgN = pBg;
    } else {
      TILE_COORD(tn, m0N, n0N);
      pAgN = A + (size_t)(m0N + rowoff) * KK + soff;
      pBgN = Bt + (size_t)(n0N + rowoff) * KK + soff;
    }

    for (int k = 0; k < NT; k += 2) {
      const u16* bS1 = pBg + (k + 1) * 64;   // k+1 <= NT-1 always
      const u16* aS2 = (k + 2 < NT) ? pAg + (k + 2) * 64 : pAgN + (k + 2 - NT) * 64;
      TBX(0, bS1, aS2);
      const u16* bS2 = (k + 2 < NT) ? pBg + (k + 2) * 64 : pBgN + (k + 2 - NT) * 64;
      const u16* aS3 = (k + 3 < NT) ? pAg + (k + 3) * 64 : pAgN + (k + 3 - NT) * 64;
      TBX(1, bS2, aS3);
    }

    EPI(m0, n0);
    if (last) break;
    t = tn; m0 = m0N; n0 = n0N; pAg = pAgN; pBg = pBgN;
    ZERO_ACC;
  }
  asm volatile("s_waitcnt vmcnt(0)");   // drain dummy LDS-DMA before exit
}

// ---------------- block-diagonal attention v2 (unchanged, validated) ----------------

__global__ __launch_bounds__(512, 2) void k_attn2(const u16* __restrict__ qkv,
                                                  u16* __restrict__ o) {
  __shared__ u16 ldsK[256 * 64];
  __shared__ u16 ldsV[64 * 256];

  int bid = blockIdx.x;
  int g = ((bid & 7) << 7) | (bid >> 3);
  int blk = g & 15, h = (g >> 4) & 15, b = g >> 8;

  int tid = threadIdx.x;
  int w = tid >> 6, lane = tid & 63;
  int hgrp = lane >> 4;
  size_t rowb = ((size_t)(b * 4096 + blk * 256)) * 3072 + (size_t)h * 192;

  int qbase = w * 32;
  const u16* qp0 = qkv + rowb + (size_t)(qbase + (lane & 15)) * 3072 + hgrp * 8;
  const u16* qp1 = qp0 + (size_t)16 * 3072;
  bf16x8 qf00 = *(const bf16x8*)(qp0);
  bf16x8 qf01 = *(const bf16x8*)(qp0 + 32);
  bf16x8 qf10 = *(const bf16x8*)(qp1);
  bf16x8 qf11 = *(const bf16x8*)(qp1 + 32);

#pragma unroll
  for (int it = 0; it < 4; ++it) {
    int trow = it * 64 + (tid >> 3);
    const u16* ksrc = qkv + rowb + (size_t)trow * 3072 + 64 +
                      (((lane & 7) ^ (lane >> 3)) << 3);
    async_ld16(ksrc, ldsK + (it * 64 + w * 8) * 64);
    int d0 = (tid & 7) << 3;
    uint4 vv = *(const uint4*)(qkv + rowb + (size_t)trow * 3072 + 128 + d0);
    union { uint4 v; u16 s[8]; } uv;
    uv.v = vv;
#pragma unroll
    for (int j = 0; j < 8; ++j) {
      int d = d0 + j;
      int key = (((d & 7) ^ ((d >> 3) & 7)) & 7) << 4;
      *(u16*)((char*)ldsV + d * 512 + ((2 * trow) ^ key)) = uv.s[j];
    }
  }
  __syncthreads();

  f32x4 acc0[16] = {}, acc1[16] = {};
  int cb = hgrp << 4;
#pragma unroll
  for (int ct = 0; ct < 16; ++ct) {
    int krow = ct * 16 + (lane & 15);
    const char* kb = (const char*)ldsK + krow * 128;
    int key = (krow & 7) << 4;
    bf16x8 k0 = *(const bf16x8*)(kb + (cb ^ key));
    bf16x8 k1 = *(const bf16x8*)(kb + ((64 + cb) ^ key));
    acc0[ct] = __builtin_amdgcn_mfma_f32_16x16x32_bf16(k0, qf00, acc0[ct], 0, 0, 0);
    acc0[ct] = __builtin_amdgcn_mfma_f32_16x16x32_bf16(k1, qf01, acc0[ct], 0, 0, 0);
    acc1[ct] = __builtin_amdgcn_mfma_f32_16x16x32_bf16(k0, qf10, acc1[ct], 0, 0, 0);
    acc1[ct] = __builtin_amdgcn_mfma_f32_16x16x32_bf16(k1, qf11, acc1[ct], 0, 0, 0);
  }

  const float SC = 0.125f * 1.44269504f;
  float rden0, rden1;
  {
    float mx = -1e30f;
#pragma unroll
    for (int ct = 0; ct < 16; ++ct)
#pragma unroll
      for (int rg = 0; rg < 4; ++rg) mx = fmaxf(mx, acc0[ct][rg]);
    mx = fmaxf(mx, __shfl_xor(mx, 16));
    mx = fmaxf(mx, __shfl_xor(mx, 32));
    float s = 0.f;
#pragma unroll
    for (int ct = 0; ct < 16; ++ct)
#pragma unroll
      for (int rg = 0; rg < 4; ++rg) {
        float p = exp2f((acc0[ct][rg] - mx) * SC);
        acc0[ct][rg] = p;
        s += p;
      }
    s += __shfl_xor(s, 16);
    s += __shfl_xor(s, 32);
    rden0 = 1.f / s;
  }
  {
    float mx = -1e30f;
#pragma unroll
    for (int ct = 0; ct < 16; ++ct)
#pragma unroll
      for (int rg = 0; rg < 4; ++rg) mx = fmaxf(mx, acc1[ct][rg]);
    mx = fmaxf(mx, __shfl_xor(mx, 16));
    mx = fmaxf(mx, __shfl_xor(mx, 32));
    float s = 0.f;
#pragma unroll
    for (int ct = 0; ct < 16; ++ct)
#pragma unroll
      for (int rg = 0; rg < 4; ++rg) {
        float p = exp2f((acc1[ct][rg] - mx) * SC);
        acc1[ct][rg] = p;
        s += p;
      }
    s += __shfl_xor(s, 16);
    s += __shfl_xor(s, 32);
    rden1 = 1.f / s;
  }

  int s1 = (lane & 15) + ((lane >> 4) & 1) * 32;
  int s2 = s1 + 16;
  bool lo = (lane < 32);
  bf16x8 pa0[8], pa1[8];
#define PCONV(ACC, PA)                                                      \
  _Pragma("unroll") for (int kt = 0; kt < 8; ++kt) {                        \
    u32 wA0, wB0, wA1, wB1;                                                 \
    asm("v_cvt_pk_bf16_f32 %0, %1, %2" : "=v"(wA0)                          \
        : "v"(ACC[2 * kt][0]), "v"(ACC[2 * kt][1]));                        \
    asm("v_cvt_pk_bf16_f32 %0, %1, %2" : "=v"(wB0)                          \
        : "v"(ACC[2 * kt][2]), "v"(ACC[2 * kt][3]));                        \
    asm("v_cvt_pk_bf16_f32 %0, %1, %2" : "=v"(wA1)                          \
        : "v"(ACC[2 * kt + 1][0]), "v"(ACC[2 * kt + 1][1]));                \
    asm("v_cvt_pk_bf16_f32 %0, %1, %2" : "=v"(wB1)                          \
        : "v"(ACC[2 * kt + 1][2]), "v"(ACC[2 * kt + 1][3]));                \
    u32 t0a = (u32)__shfl((int)wA0, s1), t0b = (u32)__shfl((int)wA1, s1);   \
    u32 t1a = (u32)__shfl((int)wB0, s1), t1b = (u32)__shfl((int)wB1, s1);   \
    u32 t2a = (u32)__shfl((int)wA0, s2), t2b = (u32)__shfl((int)wA1, s2);   \
    u32 t3a = (u32)__shfl((int)wB0, s2), t3b = (u32)__shfl((int)wB1, s2);   \
    union { u32 w[4]; bf16x8 v; } pu;                                       \
    pu.w[0] = lo ? t0a : t0b;                                               \
    pu.w[1] = lo ? t1a : t1b;                                               \
    pu.w[2] = lo ? t2a : t2b;                                               \
    pu.w[3] = lo ? t3a : t3b;                                               \
    PA[kt] = pu.v;                                                          \
  }
  PCONV(acc0, pa0)
  PCONV(acc1, pa1)
#undef PCONV

  f32x4 oa0[4] = {}, oa1[4] = {};
#pragma unroll
  for (int kt = 0; kt < 8; ++kt) {
    int vkb = 2 * (kt * 32 + hgrp * 8);
#pragma unroll
    for (int nt = 0; nt < 4; ++nt) {
      int vd = nt * 16 + (lane & 15);
      int key = (((vd & 7) ^ ((vd >> 3) & 7)) & 7) << 4;
      bf16x8 vf = *(const bf16x8*)((char*)ldsV + vd * 512 + (vkb ^ key));
      oa0[nt] = __builtin_amdgcn_mfma_f32_16x16x32_bf16(pa0[kt], vf, oa0[nt], 0, 0, 0);
      oa1[nt] = __builtin_amdgcn_mfma_f32_16x16x32_bf16(pa1[kt], vf, oa1[nt], 0, 0, 0);
    }
  }

  float rd0[4], rd1[4];
#pragma unroll
  for (int rg = 0; rg < 4; ++rg) {
    rd0[rg] = __shfl(rden0, 4 * hgrp + rg, 16);
    rd1[rg] = __shfl(rden1, 4 * hgrp + rg, 16);
  }
  size_t ob = ((size_t)(b * 4096 + blk * 256 + qbase)) * 1024 + (size_t)h * 64;
#pragma unroll
  for (int nt = 0; nt < 4; ++nt)
#pragma unroll
    for (int rg = 0; rg < 4; ++rg) {
      int col = nt * 16 + (lane & 15);
      o[ob + (size_t)(4 * hgrp + rg) * 1024 + col] = f2bf(oa0[nt][rg] * rd0[rg]);
      o[ob + (size_t)(16 + 4 * hgrp + rg) * 1024 + col] = f2bf(oa1[nt][rg] * rd1[rg]);
    }
}

// ---------------- launch ----------------

extern "C" void kernel_launch(void* const* d_in, const int* in_sizes, int n_in,
                              void* d_out, int out_size, void* d_ws, size_t ws_size,
                              hipStream_t stream) {
  (void)in_sizes; (void)n_in; (void)out_size; (void)ws_size;
  const float* x = (const float*)d_in[0];
  const float* Wqkv = (const float*)d_in[1];
  const float* bqkv = (const float*)d_in[2];
  const float* Wout = (const float*)d_in[3];
  const float* bout = (const float*)d_in[4];
  float* out = (float*)d_out;

  char* ws = (char*)d_ws;
  u16* xb    = (u16*)(ws + 0);
  u16* wqkvT = (u16*)(ws + 33554432);
  u16* woT   = (u16*)(ws + 39845888);
  u16* qkv   = (u16*)(ws + 41943040);
  u16* ob    = (u16*)(ws + 142606336);

  hipFuncSetAttribute(reinterpret_cast<const void*>(&k_gemm8<1, 1024>),
                      hipFuncAttributeMaxDynamicSharedMemorySize, 131072);
  hipFuncSetAttribute(reinterpret_cast<const void*>(&k_gemm8<0, 1024>),
                      hipFuncAttributeMaxDynamicSharedMemorySize, 131072);

  k_cvt_bf16<<<8192, 256, 0, stream>>>(x, xb, 16384 * 1024 / 8);
  k_transpose_cvt<<<dim3(96, 32), dim3(32, 8), 0, stream>>>(Wqkv, wqkvT, 1024, 3072);
  k_transpose_cvt<<<dim3(32, 32), dim3(32, 8), 0, stream>>>(Wout, woT, 1024, 1024);

  // qkv = x @ Wqkv + bqkv (bf16 out): 768 tiles, persistent over 256 WGs
  k_gemm8<1, 1024><<<256, 512, 131072, stream>>>(xb, wqkvT, bqkv, qkv, 16384, 3072);

  // block-diagonal attention: one WG per (b,h,blk)
  k_attn2<<<1024, 512, 0, stream>>>(qkv, ob);

  // out = o @ Wout + bout (fp32 out): 256 tiles
  k_gemm8<0, 1024><<<256, 512, 131072, stream>>>(ob, woT, bout, out, 16384, 1024);
}